// Round 3
// baseline (713.293 us; speedup 1.0000x reference)
//
#include <hip/hip_runtime.h>

// StargazerGNN: 3-layer GCN + graph mean-pool + linear head.
// N=100000 nodes, E=1600000 edges, G=64 graphs, D=128.
// R2: (1) h stored fp16 (halves gather traffic; tolerance 4.6e-3 >> fp16 err)
//     (2) two-phase bucketed CSR build w/ deterministic scan (kills the 105MB
//         write amplification seen in k_scatter: WRITE_SIZE 105MB -> ~20MB)
//     (3) agg fused into mm (drops Bm global round-trip, ~50MB/layer)

#define DHID 128
#define NGRAPH 64

typedef _Float16 half8 __attribute__((ext_vector_type(8)));
typedef _Float16 half4 __attribute__((ext_vector_type(4)));

__device__ __forceinline__ void fma4(float4& a, float s, const float4& w) {
  a.x = fmaf(s, w.x, a.x);
  a.y = fmaf(s, w.y, a.y);
  a.z = fmaf(s, w.z, a.z);
  a.w = fmaf(s, w.w, a.w);
}

// ---- CSR build ----
// Degree count (int atomics, distributed over N addresses).
__global__ void k_deg(const int* __restrict__ src, const int* __restrict__ dst,
                      int* __restrict__ degout, int* __restrict__ degin, int E) {
  int e = blockIdx.x * 256 + threadIdx.x;
  if (e < E) {
    atomicAdd(&degout[src[e]], 1);
    atomicAdd(&degin[dst[e]], 1);
  }
}

// Per-256-node-block degree sums.
__global__ __launch_bounds__(256) void k_bsum(const int* __restrict__ degin,
                                              int* __restrict__ bsum, int N) {
  __shared__ int ws[4];
  int tid = threadIdx.x;
  int n = blockIdx.x * 256 + tid;
  int v = (n < N) ? degin[n] : 0;
#pragma unroll
  for (int s = 32; s >= 1; s >>= 1) v += __shfl_down(v, s, 64);
  if ((tid & 63) == 0) ws[tid >> 6] = v;
  __syncthreads();
  if (tid == 0) bsum[blockIdx.x] = ws[0] + ws[1] + ws[2] + ws[3];
}

// Single-block exclusive scan of <=1024 block sums (N=100K -> 391 blocks).
__global__ __launch_bounds__(1024) void k_bscan(int* __restrict__ bsum, int nb) {
  __shared__ int ws[16];
  int tid = threadIdx.x;
  int v = (tid < nb) ? bsum[tid] : 0;
  int incl = v;
#pragma unroll
  for (int s = 1; s < 64; s <<= 1) {
    int u = __shfl_up(incl, s, 64);
    if ((tid & 63) >= s) incl += u;
  }
  if ((tid & 63) == 63) ws[tid >> 6] = incl;
  __syncthreads();
  if (tid < 16) {
    int x = ws[tid];
#pragma unroll
    for (int s = 1; s < 16; s <<= 1) {
      int u = __shfl_up(x, s, 16);
      if (tid >= s) x += u;
    }
    ws[tid] = x;
  }
  __syncthreads();
  int wbase = (tid >> 6) == 0 ? 0 : ws[(tid >> 6) - 1];
  if (tid < nb) bsum[tid] = wbase + incl - v;  // exclusive
}

// off[n] = deterministic prefix sum of degin; also bucket cursors (64 nodes/
// bucket) and per-graph node counts (LDS reduction).
__global__ __launch_bounds__(256) void k_off2(
    const int* __restrict__ degin, const int* __restrict__ gid,
    const int* __restrict__ bbase, int* __restrict__ off, int* __restrict__ cur,
    int* __restrict__ bcur, float* __restrict__ countsF, int N) {
  __shared__ int wsum[4];
  __shared__ float lcounts[NGRAPH];
  const int tid = threadIdx.x;
  const int n = blockIdx.x * 256 + tid;
  const int lane = tid & 63;
  const int wave = tid >> 6;

  int d = (n < N) ? degin[n] : 0;
  int val = d;
#pragma unroll
  for (int s = 1; s < 64; s <<= 1) {
    int up = __shfl_up(val, s, 64);
    if (lane >= s) val += up;
  }
  if (lane == 63) wsum[wave] = val;
  if (tid < NGRAPH) lcounts[tid] = 0.0f;
  __syncthreads();
  if (tid == 0) {
    int base = bbase[blockIdx.x];
    int s0 = wsum[0], s1 = wsum[1], s2 = wsum[2];
    wsum[3] = base + s0 + s1 + s2;
    wsum[2] = base + s0 + s1;
    wsum[1] = base + s0;
    wsum[0] = base;
  }
  __syncthreads();
  if (n < N) {
    int o = wsum[wave] + (val - d);
    off[n] = o;
    cur[n] = o;
    if ((n & 63) == 0) bcur[n >> 6] = o;  // bucket base cursor
    atomicAdd(&lcounts[gid[n]], 1.0f);
  }
  __syncthreads();
  if (tid < NGRAPH) {
    float c = lcounts[tid];
    if (c != 0.0f) atomicAdd(&countsF[tid], c);
  }
}

// Phase B: scatter edges into dst-buckets (sequential within bucket -> line-
// filling writes, no amplification).
__global__ void k_bucket(const int* __restrict__ src, const int* __restrict__ dst,
                         int* __restrict__ bcur, uint2* __restrict__ stage, int E) {
  int e = blockIdx.x * 256 + threadIdx.x;
  if (e < E) {
    int d = dst[e];
    int p = atomicAdd(&bcur[d >> 6], 1);
    stage[p] = make_uint2((unsigned)src[e], (unsigned)d);
  }
}

// Phase C: place within bucket (writes land in ~4KB contiguous window).
__global__ void k_place(const uint2* __restrict__ stage, int* __restrict__ cur,
                        int* __restrict__ eidx, int E) {
  int e = blockIdx.x * 256 + threadIdx.x;
  if (e < E) {
    uint2 s = stage[e];
    int p = atomicAdd(&cur[s.y], 1);
    eidx[p] = (int)s.x;
  }
}

// ---- Layer 1 (rank-1) ----
__global__ void k_l1_agg(const int* __restrict__ degin, const int* __restrict__ degout,
                         const int* __restrict__ off, const int* __restrict__ eidx,
                         float* __restrict__ agg1, int N) {
  int n = blockIdx.x * 256 + threadIdx.x;
  if (n >= N) return;
  int o = off[n], c = degin[n];
  float acc = 0.0f;
  for (int i = 0; i < c; ++i) {
    int s = eidx[o + i];
    acc += (float)degin[s] * rsqrtf(fmaxf((float)degout[s], 1.0f));
  }
  agg1[n] = acc;
}

// hA[n][j] = relu(agg1[n]*nd*W1[j] + b1[j]) * ns, stored fp16.
__global__ void k_l1_h(const int* __restrict__ degin, const int* __restrict__ degout,
                       const float* __restrict__ agg1, const float* __restrict__ W1,
                       const float* __restrict__ b1, _Float16* __restrict__ hA, int N) {
  int idx = blockIdx.x * 256 + threadIdx.x;  // N*16 half8 slots
  int n = idx >> 4, c = idx & 15;
  if (n >= N) return;
  float nd = rsqrtf(fmaxf((float)degin[n], 1.0f));
  float ns = rsqrtf(fmaxf((float)degout[n], 1.0f));
  float x = agg1[n] * nd;
  half8 r;
#pragma unroll
  for (int j = 0; j < 8; ++j) {
    float w = W1[c * 8 + j];
    float b = b1[c * 8 + j];
    r[j] = (_Float16)(fmaxf(fmaf(x, w, b), 0.0f) * ns);
  }
  *(half8*)(hA + (size_t)n * DHID + c * 8) = r;
}

// ---- Fused per-layer kernel: CSR-aggregate 32 nodes into LDS, then dense
// 128x128 matmul. MODE==1 fuses the graph mean-pool numerator. ----
template <int MODE>
__global__ __launch_bounds__(256) void k_agg_mm(
    const _Float16* __restrict__ hs, const int* __restrict__ off,
    const int* __restrict__ degin, const int* __restrict__ degout,
    const int* __restrict__ eidx, const float* __restrict__ W,
    const float* __restrict__ bias, _Float16* __restrict__ hOut,
    const int* __restrict__ gid, float* __restrict__ hg, int N) {
  __shared__ float xl[32][DHID];
  const int tid = threadIdx.x;
  const int base = blockIdx.x * 32;
  const int g16 = tid >> 4;   // 16 groups of 16 lanes
  const int l16 = tid & 15;

  // Aggregate: each 16-lane group does 2 nodes; lane handles 8 dims (16B gathers).
#pragma unroll
  for (int rep = 0; rep < 2; ++rep) {
    int n = g16 + rep * 16;
    int node = base + n;
    float acc[8] = {0.f, 0.f, 0.f, 0.f, 0.f, 0.f, 0.f, 0.f};
    if (node < N) {
      int o = off[node], c = degin[node];
      for (int i = 0; i < c; ++i) {
        int s = eidx[o + i];
        half8 v = *(const half8*)(hs + (size_t)s * DHID + l16 * 8);
#pragma unroll
        for (int j = 0; j < 8; ++j) acc[j] += (float)v[j];
      }
      float nd = rsqrtf(fmaxf((float)c, 1.0f));
#pragma unroll
      for (int j = 0; j < 8; ++j) acc[j] *= nd;
    }
#pragma unroll
    for (int j = 0; j < 8; ++j) xl[n][l16 * 8 + j] = acc[j];
  }
  __syncthreads();

  // Dense mm: thread = (ng: 8 groups x 4 nodes, jg: 32 x 4 cols).
  const int jg = tid & 31;
  const int ng = tid >> 5;
  const float* wj = W + jg * 4;

  float4 acc[4];
#pragma unroll
  for (int i = 0; i < 4; ++i) acc[i] = make_float4(0.f, 0.f, 0.f, 0.f);

#pragma unroll 4
  for (int k = 0; k < DHID; k += 4) {
    float4 w0 = *(const float4*)(wj + (size_t)(k + 0) * DHID);
    float4 w1 = *(const float4*)(wj + (size_t)(k + 1) * DHID);
    float4 w2 = *(const float4*)(wj + (size_t)(k + 2) * DHID);
    float4 w3 = *(const float4*)(wj + (size_t)(k + 3) * DHID);
#pragma unroll
    for (int i = 0; i < 4; ++i) {
      float4 x = *(const float4*)&xl[ng * 4 + i][k];
      fma4(acc[i], x.x, w0);
      fma4(acc[i], x.y, w1);
      fma4(acc[i], x.z, w2);
      fma4(acc[i], x.w, w3);
    }
  }

  float4 bb = *(const float4*)(bias + jg * 4);

  if (MODE == 0) {
#pragma unroll
    for (int i = 0; i < 4; ++i) {
      int node = base + ng * 4 + i;
      if (node < N) {
        float ns = rsqrtf(fmaxf((float)degout[node], 1.0f));
        half4 r;
        r[0] = (_Float16)(fmaxf(acc[i].x + bb.x, 0.0f) * ns);
        r[1] = (_Float16)(fmaxf(acc[i].y + bb.y, 0.0f) * ns);
        r[2] = (_Float16)(fmaxf(acc[i].z + bb.z, 0.0f) * ns);
        r[3] = (_Float16)(fmaxf(acc[i].w + bb.w, 0.0f) * ns);
        *(half4*)(hOut + (size_t)node * DHID + jg * 4) = r;
      }
    }
  } else {
    // h3 (unscaled, fp32) back into LDS, then fused graph-mean-pool numerator.
    __syncthreads();
#pragma unroll
    for (int i = 0; i < 4; ++i) {
      int n = ng * 4 + i;
      float4 r;
      r.x = fmaxf(acc[i].x + bb.x, 0.0f);
      r.y = fmaxf(acc[i].y + bb.y, 0.0f);
      r.z = fmaxf(acc[i].z + bb.z, 0.0f);
      r.w = fmaxf(acc[i].w + bb.w, 0.0f);
      *((float4*)&xl[n][0] + jg) = r;
    }
    __syncthreads();
    if (tid < DHID) {
      float s = 0.0f;
      int gcur = gid[base];
      for (int n = 0; n < 32; ++n) {
        int node = base + n;
        if (node >= N) break;
        int g = gid[node];
        if (g != gcur) {
          atomicAdd(&hg[gcur * DHID + tid], s);
          s = 0.0f;
          gcur = g;
        }
        s += xl[n][tid];
      }
      atomicAdd(&hg[gcur * DHID + tid], s);
    }
  }
}

// Final head: out[g][c] = (hg[g][:] @ Wc[:,c]) / clip(counts[g],1) + bc[c].
__global__ void k_out(const float* __restrict__ hg, const float* __restrict__ countsF,
                      const float* __restrict__ Wc, const float* __restrict__ bc,
                      float* __restrict__ out) {
  int t = threadIdx.x;  // 128 = 64 graphs x 2 outputs
  int g = t >> 1, c = t & 1;
  float acc = 0.0f;
  for (int d = 0; d < DHID; ++d) acc = fmaf(hg[g * DHID + d], Wc[d * 2 + c], acc);
  out[t] = acc / fmaxf(countsF[g], 1.0f) + bc[c];
}

extern "C" void kernel_launch(void* const* d_in, const int* in_sizes, int n_in,
                              void* d_out, int out_size, void* d_ws, size_t ws_size,
                              hipStream_t stream) {
  const int* src = (const int*)d_in[0];
  const int* dst = (const int*)d_in[1];
  const int* gid = (const int*)d_in[2];
  const float* W1 = (const float*)d_in[3];
  const float* b1 = (const float*)d_in[4];
  const float* W2 = (const float*)d_in[5];
  const float* b2 = (const float*)d_in[6];
  const float* W3 = (const float*)d_in[7];
  const float* b3 = (const float*)d_in[8];
  const float* Wc = (const float*)d_in[9];
  const float* bc = (const float*)d_in[10];
  float* out = (float*)d_out;
  const int E = in_sizes[0];
  const int N = in_sizes[2];
  const int NBLK = (N + 255) / 256;   // 391 (<=1024 required by k_bscan)
  const int NBUCK = (N + 63) / 64;    // 1563

  char* ws = (char*)d_ws;
  size_t o = 0;
  auto alloc = [&](size_t bytes) {
    void* p = ws + o;
    o += (bytes + 255) & ~(size_t)255;
    return p;
  };
  _Float16* hA = (_Float16*)alloc((size_t)N * DHID * 2);
  uint2* stage = (uint2*)alloc((size_t)E * 8);
  int* eidx = (int*)alloc((size_t)E * 4);
  size_t z0 = o;  // zero-init region
  int* degin = (int*)alloc((size_t)N * 4);
  int* degout = (int*)alloc((size_t)N * 4);
  float* hg = (float*)alloc((size_t)NGRAPH * DHID * 4);
  float* countsF = (float*)alloc((size_t)NGRAPH * 4);
  size_t z1 = o;  // end zero-init
  float* agg1 = (float*)alloc((size_t)N * 4);
  int* off = (int*)alloc((size_t)N * 4);
  int* cur = (int*)alloc((size_t)N * 4);
  int* bcur = (int*)alloc((size_t)NBUCK * 4);
  int* bsum = (int*)alloc(1024 * 4);
  (void)ws_size;  // ~48 MB used

  hipMemsetAsync(ws + z0, 0, z1 - z0, stream);

  // CSR build (deterministic offsets, locality-preserving scatter).
  k_deg<<<(E + 255) / 256, 256, 0, stream>>>(src, dst, degout, degin, E);
  k_bsum<<<NBLK, 256, 0, stream>>>(degin, bsum, N);
  k_bscan<<<1, 1024, 0, stream>>>(bsum, NBLK);
  k_off2<<<NBLK, 256, 0, stream>>>(degin, gid, bsum, off, cur, bcur, countsF, N);
  k_bucket<<<(E + 255) / 256, 256, 0, stream>>>(src, dst, bcur, stage, E);
  k_place<<<(E + 255) / 256, 256, 0, stream>>>(stage, cur, eidx, E);
  // Layer 1
  k_l1_agg<<<(N + 255) / 256, 256, 0, stream>>>(degin, degout, off, eidx, agg1, N);
  k_l1_h<<<((size_t)N * 16 + 255) / 256, 256, 0, stream>>>(degin, degout, agg1, W1, b1, hA, N);
  // Layer 2 (fused agg+mm), writes hA in place (read/write disjoint per node? no:
  // hA is both input and output -> use separate buffer)... see below.
  // NOTE: hs input and hOut output must be distinct buffers.
  {
    static_assert(true, "");
  }
  _Float16* hB = (_Float16*)alloc((size_t)N * DHID * 2);
  k_agg_mm<0><<<(N + 31) / 32, 256, 0, stream>>>(hA, off, degin, degout, eidx, W2, b2, hB, gid, hg, N);
  // Layer 3 (+ fused mean-pool numerator)
  k_agg_mm<1><<<(N + 31) / 32, 256, 0, stream>>>(hB, off, degin, degout, eidx, W3, b3, nullptr, gid, hg, N);
  // Head
  k_out<<<1, 128, 0, stream>>>(hg, countsF, Wc, bc, out);
}

// Round 4
// 519.934 us; speedup vs baseline: 1.3719x; 1.3719x over previous
//
#include <hip/hip_runtime.h>

// StargazerGNN: 3-layer GCN + graph mean-pool + linear head.
// N=100000 nodes, E=1600000 edges, G=64 graphs, D=128.
// R3 post-mortem: bucketed scatter kept 6x write amplification (WRITE_SIZE
// 85MB) because stage lines don't stay L2-resident while filling.
// R4: direct eidx scatter split into 4 dst-range passes -> active write
// window 1.6MB (L2-resident, lines fill completely) -> ~1x write traffic.

#define DHID 128
#define NGRAPH 64
#define NPASS 4

typedef _Float16 half8 __attribute__((ext_vector_type(8)));
typedef _Float16 half4 __attribute__((ext_vector_type(4)));

__device__ __forceinline__ void fma4(float4& a, float s, const float4& w) {
  a.x = fmaf(s, w.x, a.x);
  a.y = fmaf(s, w.y, a.y);
  a.z = fmaf(s, w.z, a.z);
  a.w = fmaf(s, w.w, a.w);
}

// ---- CSR build ----
__global__ void k_deg(const int* __restrict__ src, const int* __restrict__ dst,
                      int* __restrict__ degout, int* __restrict__ degin, int E) {
  int e = blockIdx.x * 256 + threadIdx.x;
  if (e < E) {
    atomicAdd(&degout[src[e]], 1);
    atomicAdd(&degin[dst[e]], 1);
  }
}

// Per-256-node-block degree sums.
__global__ __launch_bounds__(256) void k_bsum(const int* __restrict__ degin,
                                              int* __restrict__ bsum, int N) {
  __shared__ int ws[4];
  int tid = threadIdx.x;
  int n = blockIdx.x * 256 + tid;
  int v = (n < N) ? degin[n] : 0;
#pragma unroll
  for (int s = 32; s >= 1; s >>= 1) v += __shfl_down(v, s, 64);
  if ((tid & 63) == 0) ws[tid >> 6] = v;
  __syncthreads();
  if (tid == 0) bsum[blockIdx.x] = ws[0] + ws[1] + ws[2] + ws[3];
}

// Single-block exclusive scan of <=1024 block sums (N=100K -> 391 blocks).
__global__ __launch_bounds__(1024) void k_bscan(int* __restrict__ bsum, int nb) {
  __shared__ int ws[16];
  int tid = threadIdx.x;
  int v = (tid < nb) ? bsum[tid] : 0;
  int incl = v;
#pragma unroll
  for (int s = 1; s < 64; s <<= 1) {
    int u = __shfl_up(incl, s, 64);
    if ((tid & 63) >= s) incl += u;
  }
  if ((tid & 63) == 63) ws[tid >> 6] = incl;
  __syncthreads();
  if (tid < 16) {
    int x = ws[tid];
#pragma unroll
    for (int s = 1; s < 16; s <<= 1) {
      int u = __shfl_up(x, s, 16);
      if (tid >= s) x += u;
    }
    ws[tid] = x;
  }
  __syncthreads();
  int wbase = (tid >> 6) == 0 ? 0 : ws[(tid >> 6) - 1];
  if (tid < nb) bsum[tid] = wbase + incl - v;  // exclusive
}

// off[n] = deterministic prefix sum of degin; cur init; per-graph node counts.
__global__ __launch_bounds__(256) void k_off2(
    const int* __restrict__ degin, const int* __restrict__ gid,
    const int* __restrict__ bbase, int* __restrict__ off, int* __restrict__ cur,
    float* __restrict__ countsF, int N) {
  __shared__ int wsum[4];
  __shared__ float lcounts[NGRAPH];
  const int tid = threadIdx.x;
  const int n = blockIdx.x * 256 + tid;
  const int lane = tid & 63;
  const int wave = tid >> 6;

  int d = (n < N) ? degin[n] : 0;
  int val = d;
#pragma unroll
  for (int s = 1; s < 64; s <<= 1) {
    int up = __shfl_up(val, s, 64);
    if (lane >= s) val += up;
  }
  if (lane == 63) wsum[wave] = val;
  if (tid < NGRAPH) lcounts[tid] = 0.0f;
  __syncthreads();
  if (tid == 0) {
    int base = bbase[blockIdx.x];
    int s0 = wsum[0], s1 = wsum[1], s2 = wsum[2];
    wsum[3] = base + s0 + s1 + s2;
    wsum[2] = base + s0 + s1;
    wsum[1] = base + s0;
    wsum[0] = base;
  }
  __syncthreads();
  if (n < N) {
    int o = wsum[wave] + (val - d);
    off[n] = o;
    cur[n] = o;
    atomicAdd(&lcounts[gid[n]], 1.0f);
  }
  __syncthreads();
  if (tid < NGRAPH) {
    float c = lcounts[tid];
    if (c != 0.0f) atomicAdd(&countsF[tid], c);
  }
}

// Direct scatter, restricted to dst in [lo, hi): active eidx window ~1.6MB
// stays L2-resident so write lines fill completely (no amplification).
__global__ void k_scatter(const int* __restrict__ src, const int* __restrict__ dst,
                          int* __restrict__ cur, int* __restrict__ eidx, int E,
                          int lo, int hi) {
  int e = blockIdx.x * 256 + threadIdx.x;
  if (e < E) {
    int d = dst[e];
    if (d >= lo && d < hi) {
      int p = atomicAdd(&cur[d], 1);
      eidx[p] = src[e];
    }
  }
}

// ---- Layer 1 (rank-1) ----
__global__ void k_l1_agg(const int* __restrict__ degin, const int* __restrict__ degout,
                         const int* __restrict__ off, const int* __restrict__ eidx,
                         float* __restrict__ agg1, int N) {
  int n = blockIdx.x * 256 + threadIdx.x;
  if (n >= N) return;
  int o = off[n], c = degin[n];
  float acc = 0.0f;
  for (int i = 0; i < c; ++i) {
    int s = eidx[o + i];
    acc += (float)degin[s] * rsqrtf(fmaxf((float)degout[s], 1.0f));
  }
  agg1[n] = acc;
}

// hA[n][j] = relu(agg1[n]*nd*W1[j] + b1[j]) * ns, stored fp16.
__global__ void k_l1_h(const int* __restrict__ degin, const int* __restrict__ degout,
                       const float* __restrict__ agg1, const float* __restrict__ W1,
                       const float* __restrict__ b1, _Float16* __restrict__ hA, int N) {
  int idx = blockIdx.x * 256 + threadIdx.x;  // N*16 half8 slots
  int n = idx >> 4, c = idx & 15;
  if (n >= N) return;
  float nd = rsqrtf(fmaxf((float)degin[n], 1.0f));
  float ns = rsqrtf(fmaxf((float)degout[n], 1.0f));
  float x = agg1[n] * nd;
  half8 r;
#pragma unroll
  for (int j = 0; j < 8; ++j) {
    float w = W1[c * 8 + j];
    float b = b1[c * 8 + j];
    r[j] = (_Float16)(fmaxf(fmaf(x, w, b), 0.0f) * ns);
  }
  *(half8*)(hA + (size_t)n * DHID + c * 8) = r;
}

// ---- Fused per-layer kernel: CSR-aggregate 32 nodes into LDS, then dense
// 128x128 matmul. MODE==1 fuses the graph mean-pool numerator. ----
template <int MODE>
__global__ __launch_bounds__(256) void k_agg_mm(
    const _Float16* __restrict__ hs, const int* __restrict__ off,
    const int* __restrict__ degin, const int* __restrict__ degout,
    const int* __restrict__ eidx, const float* __restrict__ W,
    const float* __restrict__ bias, _Float16* __restrict__ hOut,
    const int* __restrict__ gid, float* __restrict__ hg, int N) {
  __shared__ float xl[32][DHID];
  const int tid = threadIdx.x;
  const int base = blockIdx.x * 32;
  const int g16 = tid >> 4;   // 16 groups of 16 lanes
  const int l16 = tid & 15;

  // Aggregate: each 16-lane group does 2 nodes; lane handles 8 dims (16B gathers).
#pragma unroll
  for (int rep = 0; rep < 2; ++rep) {
    int n = g16 + rep * 16;
    int node = base + n;
    float acc[8] = {0.f, 0.f, 0.f, 0.f, 0.f, 0.f, 0.f, 0.f};
    if (node < N) {
      int o = off[node], c = degin[node];
      for (int i = 0; i < c; ++i) {
        int s = eidx[o + i];
        half8 v = *(const half8*)(hs + (size_t)s * DHID + l16 * 8);
#pragma unroll
        for (int j = 0; j < 8; ++j) acc[j] += (float)v[j];
      }
      float nd = rsqrtf(fmaxf((float)c, 1.0f));
#pragma unroll
      for (int j = 0; j < 8; ++j) acc[j] *= nd;
    }
#pragma unroll
    for (int j = 0; j < 8; ++j) xl[n][l16 * 8 + j] = acc[j];
  }
  __syncthreads();

  // Dense mm: thread = (ng: 8 groups x 4 nodes, jg: 32 x 4 cols).
  const int jg = tid & 31;
  const int ng = tid >> 5;
  const float* wj = W + jg * 4;

  float4 acc[4];
#pragma unroll
  for (int i = 0; i < 4; ++i) acc[i] = make_float4(0.f, 0.f, 0.f, 0.f);

#pragma unroll 4
  for (int k = 0; k < DHID; k += 4) {
    float4 w0 = *(const float4*)(wj + (size_t)(k + 0) * DHID);
    float4 w1 = *(const float4*)(wj + (size_t)(k + 1) * DHID);
    float4 w2 = *(const float4*)(wj + (size_t)(k + 2) * DHID);
    float4 w3 = *(const float4*)(wj + (size_t)(k + 3) * DHID);
#pragma unroll
    for (int i = 0; i < 4; ++i) {
      float4 x = *(const float4*)&xl[ng * 4 + i][k];
      fma4(acc[i], x.x, w0);
      fma4(acc[i], x.y, w1);
      fma4(acc[i], x.z, w2);
      fma4(acc[i], x.w, w3);
    }
  }

  float4 bb = *(const float4*)(bias + jg * 4);

  if (MODE == 0) {
#pragma unroll
    for (int i = 0; i < 4; ++i) {
      int node = base + ng * 4 + i;
      if (node < N) {
        float ns = rsqrtf(fmaxf((float)degout[node], 1.0f));
        half4 r;
        r[0] = (_Float16)(fmaxf(acc[i].x + bb.x, 0.0f) * ns);
        r[1] = (_Float16)(fmaxf(acc[i].y + bb.y, 0.0f) * ns);
        r[2] = (_Float16)(fmaxf(acc[i].z + bb.z, 0.0f) * ns);
        r[3] = (_Float16)(fmaxf(acc[i].w + bb.w, 0.0f) * ns);
        *(half4*)(hOut + (size_t)node * DHID + jg * 4) = r;
      }
    }
  } else {
    // h3 (unscaled, fp32) back into LDS, then fused graph-mean-pool numerator.
    __syncthreads();
#pragma unroll
    for (int i = 0; i < 4; ++i) {
      int n = ng * 4 + i;
      float4 r;
      r.x = fmaxf(acc[i].x + bb.x, 0.0f);
      r.y = fmaxf(acc[i].y + bb.y, 0.0f);
      r.z = fmaxf(acc[i].z + bb.z, 0.0f);
      r.w = fmaxf(acc[i].w + bb.w, 0.0f);
      *((float4*)&xl[n][0] + jg) = r;
    }
    __syncthreads();
    if (tid < DHID) {
      float s = 0.0f;
      int gcur = gid[base];
      for (int n = 0; n < 32; ++n) {
        int node = base + n;
        if (node >= N) break;
        int g = gid[node];
        if (g != gcur) {
          atomicAdd(&hg[gcur * DHID + tid], s);
          s = 0.0f;
          gcur = g;
        }
        s += xl[n][tid];
      }
      atomicAdd(&hg[gcur * DHID + tid], s);
    }
  }
}

// Final head: out[g][c] = (hg[g][:] @ Wc[:,c]) / clip(counts[g],1) + bc[c].
__global__ void k_out(const float* __restrict__ hg, const float* __restrict__ countsF,
                      const float* __restrict__ Wc, const float* __restrict__ bc,
                      float* __restrict__ out) {
  int t = threadIdx.x;  // 128 = 64 graphs x 2 outputs
  int g = t >> 1, c = t & 1;
  float acc = 0.0f;
  for (int d = 0; d < DHID; ++d) acc = fmaf(hg[g * DHID + d], Wc[d * 2 + c], acc);
  out[t] = acc / fmaxf(countsF[g], 1.0f) + bc[c];
}

extern "C" void kernel_launch(void* const* d_in, const int* in_sizes, int n_in,
                              void* d_out, int out_size, void* d_ws, size_t ws_size,
                              hipStream_t stream) {
  const int* src = (const int*)d_in[0];
  const int* dst = (const int*)d_in[1];
  const int* gid = (const int*)d_in[2];
  const float* W1 = (const float*)d_in[3];
  const float* b1 = (const float*)d_in[4];
  const float* W2 = (const float*)d_in[5];
  const float* b2 = (const float*)d_in[6];
  const float* W3 = (const float*)d_in[7];
  const float* b3 = (const float*)d_in[8];
  const float* Wc = (const float*)d_in[9];
  const float* bc = (const float*)d_in[10];
  float* out = (float*)d_out;
  const int E = in_sizes[0];
  const int N = in_sizes[2];
  const int NBLK = (N + 255) / 256;  // 391 (<=1024 required by k_bscan)

  char* ws = (char*)d_ws;
  size_t o = 0;
  auto alloc = [&](size_t bytes) {
    void* p = ws + o;
    o += (bytes + 255) & ~(size_t)255;
    return p;
  };
  _Float16* hA = (_Float16*)alloc((size_t)N * DHID * 2);
  _Float16* hB = (_Float16*)alloc((size_t)N * DHID * 2);
  int* eidx = (int*)alloc((size_t)E * 4);
  size_t z0 = o;  // zero-init region
  int* degin = (int*)alloc((size_t)N * 4);
  int* degout = (int*)alloc((size_t)N * 4);
  float* hg = (float*)alloc((size_t)NGRAPH * DHID * 4);
  float* countsF = (float*)alloc((size_t)NGRAPH * 4);
  size_t z1 = o;  // end zero-init
  float* agg1 = (float*)alloc((size_t)N * 4);
  int* off = (int*)alloc((size_t)N * 4);
  int* cur = (int*)alloc((size_t)N * 4);
  int* bsum = (int*)alloc(1024 * 4);
  (void)ws_size;  // ~60 MB used

  hipMemsetAsync(ws + z0, 0, z1 - z0, stream);

  // CSR build (deterministic offsets; range-split scatter for write locality).
  k_deg<<<(E + 255) / 256, 256, 0, stream>>>(src, dst, degout, degin, E);
  k_bsum<<<NBLK, 256, 0, stream>>>(degin, bsum, N);
  k_bscan<<<1, 1024, 0, stream>>>(bsum, NBLK);
  k_off2<<<NBLK, 256, 0, stream>>>(degin, gid, bsum, off, cur, countsF, N);
  const int span = (N + NPASS - 1) / NPASS;
  for (int p = 0; p < NPASS; ++p) {
    k_scatter<<<(E + 255) / 256, 256, 0, stream>>>(src, dst, cur, eidx, E,
                                                   p * span, (p + 1) * span);
  }
  // Layer 1
  k_l1_agg<<<(N + 255) / 256, 256, 0, stream>>>(degin, degout, off, eidx, agg1, N);
  k_l1_h<<<((size_t)N * 16 + 255) / 256, 256, 0, stream>>>(degin, degout, agg1, W1, b1, hA, N);
  // Layer 2 (fused agg+mm)
  k_agg_mm<0><<<(N + 31) / 32, 256, 0, stream>>>(hA, off, degin, degout, eidx, W2, b2, hB, gid, hg, N);
  // Layer 3 (+ fused mean-pool numerator)
  k_agg_mm<1><<<(N + 31) / 32, 256, 0, stream>>>(hB, off, degin, degout, eidx, W3, b3, nullptr, gid, hg, N);
  // Head
  k_out<<<1, 128, 0, stream>>>(hg, countsF, Wc, bc, out);
}